// Round 5
// baseline (1102.762 us; speedup 1.0000x reference)
//
#include <hip/hip_runtime.h>
#include <cstddef>

#define NN 1024
#define DD 6
#define TT 60
#define HH 64
#define NEGV  (-10000.0f)
#define SLOPEV (0.01f)

__device__ __forceinline__ float sig_(float x)  { return 1.0f / (1.0f + __expf(-x)); }
__device__ __forceinline__ float tanh_(float x) { return 1.0f - 2.0f / (__expf(2.0f * x) + 1.0f); }
__device__ __forceinline__ float rl_(float v, int l) {
    return __int_as_float(__builtin_amdgcn_readlane(__float_as_int(v), l));
}

// ---------------------------------------------------------------------------
// k_fused: 256 blocks x 768 threads (12 waves), exactly one block per CU.
//   waves 0-2 : GRU layer-0. wave = gate type (r,z,n); lane = gate row j;
//               4 samples. Whh0 row + x in registers; h0 lane-distributed,
//               broadcast via v_readlane (no LDS in the inner loop).
//   waves 3-8 : GRU layer-1, (gate-type g1, sample-pair p), 1 step behind.
//               Wih1 row + Whh1 row in registers (128 floats).
//   waves 9-11: relation streaming, 1 (i,j) pair per thread per even iter
//               (paced so HBM isn't flooded); participate in all barriers.
// Register arrays are manually unioned across the three roles to stay <=170
// VGPRs (launch_bounds(768) requires 12 waves resident).
// ---------------------------------------------------------------------------
__global__ __launch_bounds__(768)
void k_fused(const float* __restrict__ x, const float* __restrict__ rel,
             const float* __restrict__ W, const float* __restrict__ fc_w,
             const float* __restrict__ Wih0, const float* __restrict__ Whh0,
             const float* __restrict__ bih0, const float* __restrict__ bhh0,
             const float* __restrict__ Wih1, const float* __restrict__ Whh1,
             const float* __restrict__ bih1, const float* __restrict__ bhh1,
             float* __restrict__ sa, float* __restrict__ sb,
             float* __restrict__ hdot, float* __restrict__ hb,
             float* __restrict__ sr, float* __restrict__ ssum)
{
    __shared__ float smem[2048];
    float* Zb   = smem;          // L0 z preact   [s][lane]
    float* Xnb  = smem + 256;    // L0 xn preact
    float* Hnb  = smem + 512;    // L0 hn preact
    float* Z1b  = smem + 768;    // L1 z preact
    float* Xn1b = smem + 1024;   // L1 xn preact
    float* Hn1b = smem + 1280;   // L1 hn preact
    float* H0b  = smem + 1536;   // h0 state      [s][lane]
    float* H1b  = smem + 1792;   // h1 state

    const int tid  = threadIdx.x;
    const int wv   = tid >> 6;
    const int lane = tid & 63;
    const int nb   = blockIdx.x * 4;

    if (tid < 512) smem[1536 + tid] = 0.0f;   // h0 = h1 = 0

    // ---- unioned register state ----
    float wA[64];     // L0: Whh0 row | L1: Wih1 row | rel: Wv[64]
    float wB[64];     // L0: x[4][6] in [0..23], Wih0 row in [24..29] | L1: Whh1 row | rel: pair staging
    float hr[4];      // L0: h0[s][lane] s=0..3 | L1: h0[p-samples], h1[p-samples]
    float acc[8];
    float b0 = 0.f, b1 = 0.f;
    unsigned int relp = 0xFFFFFFFFu;

    hr[0] = hr[1] = hr[2] = hr[3] = 0.f;

    if (wv < 3) {
        const int row = wv * 64 + lane;
        #pragma unroll
        for (int q = 0; q < 16; ++q) {
            const float4 v = *(const float4*)(Whh0 + (size_t)row * HH + q * 4);
            wA[4*q] = v.x; wA[4*q+1] = v.y; wA[4*q+2] = v.z; wA[4*q+3] = v.w;
        }
        #pragma unroll
        for (int s = 0; s < 4; ++s)
            #pragma unroll
            for (int d = 0; d < DD; ++d)
                wB[s*6+d] = (lane < TT) ? x[(size_t)(nb + s) * DD * TT + d * TT + lane] : 0.f;
        #pragma unroll
        for (int d = 0; d < DD; ++d) wB[24 + d] = Wih0[row * DD + d];
        b0 = bih0[row]; b1 = bhh0[row];
    } else if (wv < 9) {
        const int u = wv - 3, g1 = u >> 1;
        const int row = g1 * 64 + lane;
        #pragma unroll
        for (int q = 0; q < 16; ++q) {
            const float4 a = *(const float4*)(Wih1 + (size_t)row * HH + q * 4);
            wA[4*q] = a.x; wA[4*q+1] = a.y; wA[4*q+2] = a.z; wA[4*q+3] = a.w;
            const float4 c = *(const float4*)(Whh1 + (size_t)row * HH + q * 4);
            wB[4*q] = c.x; wB[4*q+1] = c.y; wB[4*q+2] = c.z; wB[4*q+3] = c.w;
        }
        b0 = bih1[row]; b1 = bhh1[row];
    } else {
        #pragma unroll
        for (int q = 0; q < 64; ++q) wA[q] = W[2 * HH + q];
        relp = blockIdx.x * 192 + (tid - 576);      // 0..49151
    }
    __syncthreads();

    for (int i = 0; i <= TT; ++i) {
        // ---------------- phase 1: MM / rel ----------------
        if (wv < 3) {
            if (i < TT) {
                #pragma unroll
                for (int s = 0; s < 4; ++s) { acc[s] = b1; acc[4 + s] = b0; }
                #pragma unroll
                for (int k = 0; k < 64; ++k) {
                    const float wk = wA[k];
                    acc[0] += rl_(hr[0], k) * wk;
                    acc[1] += rl_(hr[1], k) * wk;
                    acc[2] += rl_(hr[2], k) * wk;
                    acc[3] += rl_(hr[3], k) * wk;
                }
                #pragma unroll
                for (int d = 0; d < DD; ++d) {
                    const float wd = wB[24 + d];
                    acc[4] += rl_(wB[0*6+d], i) * wd;
                    acc[5] += rl_(wB[1*6+d], i) * wd;
                    acc[6] += rl_(wB[2*6+d], i) * wd;
                    acc[7] += rl_(wB[3*6+d], i) * wd;
                }
                if (wv == 1) {
                    #pragma unroll
                    for (int s = 0; s < 4; ++s) Zb[s*64+lane] = acc[s] + acc[4+s];
                } else if (wv == 2) {
                    #pragma unroll
                    for (int s = 0; s < 4; ++s) { Xnb[s*64+lane] = acc[4+s]; Hnb[s*64+lane] = acc[s]; }
                }
                // wv==0 keeps r preact in acc
            }
        } else if (wv < 9) {
            if (i >= 1) {
                const int u = wv - 3, g1 = u >> 1, p = u & 1;
                acc[0] = b1; acc[1] = b1; acc[4] = b0; acc[5] = b0;
                #pragma unroll
                for (int k = 0; k < 64; ++k) {
                    const float wa = wA[k], wc = wB[k];
                    acc[4] += rl_(hr[0], k) * wa;   // Wih1 . h0
                    acc[5] += rl_(hr[1], k) * wa;
                    acc[0] += rl_(hr[2], k) * wc;   // Whh1 . h1
                    acc[1] += rl_(hr[3], k) * wc;
                }
                if (g1 == 1) {
                    Z1b[(2*p+0)*64+lane] = acc[0] + acc[4];
                    Z1b[(2*p+1)*64+lane] = acc[1] + acc[5];
                } else if (g1 == 2) {
                    Xn1b[(2*p+0)*64+lane] = acc[4]; Hn1b[(2*p+0)*64+lane] = acc[0];
                    Xn1b[(2*p+1)*64+lane] = acc[5]; Hn1b[(2*p+1)*64+lane] = acc[1];
                }
            }
        } else {
            if ((i & 1) == 0 && relp < (unsigned)(NN * NN)) {
                const float4* base = (const float4*)(rel + (size_t)relp * 64);
                #pragma unroll
                for (int q = 0; q < 16; ++q) {
                    const float4 v = base[q];
                    wB[4*q] = v.x; wB[4*q+1] = v.y; wB[4*q+2] = v.z; wB[4*q+3] = v.w;
                }
                float d0 = 0.f, d1 = 0.f, s0 = 0.f, s1 = 0.f;
                #pragma unroll
                for (int q = 0; q < 64; q += 2) {
                    d0 += wB[q] * wA[q]; d1 += wB[q+1] * wA[q+1];
                    s0 += wB[q];         s1 += wB[q+1];
                }
                sr[relp]   = d0 + d1;
                ssum[relp] = s0 + s1;
                relp += 49152;
            }
        }
        __syncthreads();

        // ---------------- phase 2: activations ----------------
        if (wv == 0 && i < TT) {
            #pragma unroll
            for (int s = 0; s < 4; ++s) {
                const float r  = sig_(acc[s] + acc[4+s]);
                const float z  = sig_(Zb[s*64+lane]);
                const float hn = Hnb[s*64+lane];
                const float nv = tanh_(Xnb[s*64+lane] + r * hn);
                H0b[s*64+lane] = (1.f - z) * nv + z * hr[s];
            }
        }
        if ((wv == 3 || wv == 4) && i >= 1) {
            const int p = wv - 3;
            #pragma unroll
            for (int ss = 0; ss < 2; ++ss) {
                const int s = 2*p + ss;
                const float r1  = sig_(acc[ss] + acc[4+ss]);
                const float z1  = sig_(Z1b[s*64+lane]);
                const float hn1 = Hn1b[s*64+lane];
                const float nv1 = tanh_(Xn1b[s*64+lane] + r1 * hn1);
                H1b[s*64+lane] = (1.f - z1) * nv1 + z1 * hr[2+ss];
            }
        }
        __syncthreads();

        // ---------------- refresh lane-distributed state ----------------
        if (wv < 3) {
            #pragma unroll
            for (int s = 0; s < 4; ++s) hr[s] = H0b[s*64+lane];
        } else if (wv < 9) {
            const int p = (wv - 3) & 1;
            hr[0] = H0b[(2*p+0)*64+lane];
            hr[1] = H0b[(2*p+1)*64+lane];
            hr[2] = H1b[(2*p+0)*64+lane];
            hr[3] = H1b[(2*p+1)*64+lane];
        }
    }

    // ---------------- epilogue: per-sample scalars (wave 0) ----------------
    if (wv == 0) {
        #pragma unroll
        for (int s = 0; s < 4; ++s) {
            const float hv = H1b[s*64+lane];
            float pa = hv * W[lane];
            float pb = hv * W[HH + lane];
            float pc = hv * fc_w[lane];
            float pd = hv * fc_w[HH + lane];
            #pragma unroll
            for (int off = 32; off >= 1; off >>= 1) {
                pa += __shfl_down(pa, off);
                pb += __shfl_down(pb, off);
                pc += __shfl_down(pc, off);
                pd += __shfl_down(pd, off);
            }
            if (lane == 0) {
                sa[nb + s] = pa; sb[nb + s] = pb;
                hdot[nb + s] = pc; hb[nb + s] = pd;
            }
        }
    }
}

// ---------------------------------------------------------------------------
// k2: per row i — masked leaky scores, exact masked-softmax semantics,
// out_i = hdot_i + (sum_j e_j*m_j*hb_j)/denom + fc_b.
// ---------------------------------------------------------------------------
__global__ __launch_bounds__(256)
void k2(const float* __restrict__ sa, const float* __restrict__ sb,
        const float* __restrict__ hdot, const float* __restrict__ hb,
        const float* __restrict__ sr, const float* __restrict__ ssum,
        const float* __restrict__ bscal, const float* __restrict__ fc_b,
        float* __restrict__ out)
{
    __shared__ float red[12];
    const int i   = blockIdx.x;
    const int tid = threadIdx.x;
    const int j4  = tid * 4;
    const float sai = sa[i] + bscal[0];

    const float4 srv = *(const float4*)(sr   + (size_t)i * NN + j4);
    const float4 ssv = *(const float4*)(ssum + (size_t)i * NN + j4);
    const float4 sbv = *(const float4*)(sb + j4);

    float tv[4], mk[4];
    float mloc = -3.4e38f;
    {
        const float srq[4] = {srv.x, srv.y, srv.z, srv.w};
        const float ssq[4] = {ssv.x, ssv.y, ssv.z, ssv.w};
        const float sbq[4] = {sbv.x, sbv.y, sbv.z, sbv.w};
        #pragma unroll
        for (int q = 0; q < 4; ++q) {
            float w = sai + sbq[q] + srq[q];
            w = (w >= 0.0f) ? w : SLOPEV * w;
            const float m = (ssq[q] != 0.0f) ? 1.0f : 0.0f;
            float t = m * w;
            t = (t == 0.0f) ? NEGV : t;
            tv[q] = t; mk[q] = m;
            mloc = fmaxf(mloc, t);
        }
    }
    #pragma unroll
    for (int off = 32; off >= 1; off >>= 1) mloc = fmaxf(mloc, __shfl_xor(mloc, off));
    if ((tid & 63) == 0) red[tid >> 6] = mloc;
    __syncthreads();
    const float mx = fmaxf(fmaxf(red[0], red[1]), fmaxf(red[2], red[3]));

    const float4 hbv = *(const float4*)(hb + j4);
    const float hbq[4] = {hbv.x, hbv.y, hbv.z, hbv.w};
    float sloc = 0.0f, vloc = 0.0f;
    #pragma unroll
    for (int q = 0; q < 4; ++q) {
        const float e = __expf(tv[q] - mx);   // masked -> exp(-1e4 - mx) == 0
        sloc += e;
        vloc += e * mk[q] * hbq[q];
    }
    #pragma unroll
    for (int off = 32; off >= 1; off >>= 1) {
        sloc += __shfl_xor(sloc, off);
        vloc += __shfl_xor(vloc, off);
    }
    if ((tid & 63) == 0) { red[4 + (tid >> 6)] = sloc; red[8 + (tid >> 6)] = vloc; }
    __syncthreads();
    if (tid == 0) {
        const float denom = red[4] + red[5] + red[6] + red[7];
        const float vsum  = red[8] + red[9] + red[10] + red[11];
        out[i] = hdot[i] + vsum / denom + fc_b[0];
    }
}

// ---------------------------------------------------------------------------
extern "C" void kernel_launch(void* const* d_in, const int* in_sizes, int n_in,
                              void* d_out, int out_size, void* d_ws, size_t ws_size,
                              hipStream_t stream)
{
    const float* x     = (const float*)d_in[0];
    const float* rel   = (const float*)d_in[1];
    const float* W     = (const float*)d_in[2];
    const float* b     = (const float*)d_in[3];
    const float* fc_w  = (const float*)d_in[4];
    const float* fc_b  = (const float*)d_in[5];
    const float* Wih0  = (const float*)d_in[6];
    const float* Whh0  = (const float*)d_in[7];
    const float* bih0  = (const float*)d_in[8];
    const float* bhh0  = (const float*)d_in[9];
    const float* Wih1  = (const float*)d_in[10];
    const float* Whh1  = (const float*)d_in[11];
    const float* bih1  = (const float*)d_in[12];
    const float* bhh1  = (const float*)d_in[13];

    float* ws   = (float*)d_ws;
    float* sa   = ws;                         // 1024
    float* sb   = sa   + NN;                  // 1024
    float* hdot = sb   + NN;                  // 1024
    float* hb   = hdot + NN;                  // 1024
    float* sr   = hb   + NN;                  // 1024*1024
    float* ssum = sr   + (size_t)NN * NN;     // 1024*1024

    k_fused<<<256, 768, 0, stream>>>(x, rel, W, fc_w,
                                     Wih0, Whh0, bih0, bhh0,
                                     Wih1, Whh1, bih1, bhh1,
                                     sa, sb, hdot, hb, sr, ssum);
    k2<<<NN, 256, 0, stream>>>(sa, sb, hdot, hb, sr, ssum,
                               b, fc_b, (float*)d_out);
}